// Round 6
// baseline (1003.559 us; speedup 1.0000x reference)
//
#include <hip/hip_runtime.h>
#include <hip/hip_bf16.h>
#include <cstddef>
#include <cstdint>

typedef __hip_bfloat16 hbf;
typedef __bf16 bf16x8 __attribute__((ext_vector_type(8)));
typedef float f32x4 __attribute__((ext_vector_type(4)));

// bn: y = x*s + t, s = g*rsqrt(v+eps), t = b - m*s
__device__ __forceinline__ void bn_coef(const float* __restrict__ p, int C, int c,
                                        float& s, float& t) {
    float g = p[c];
    float b = p[C + c];
    float m = p[2 * C + c];
    float v = p[3 * C + c];
    s = g * rsqrtf(v + 1e-5f);
    t = b - m * s;
}

// ---------------- zero-fill (dwords) --------------------------------------------
__global__ void k_fill0(uint32_t* __restrict__ p, int n) {
    int i = blockIdx.x * blockDim.x + threadIdx.x;
    if (i < n) p[i] = 0u;
}

// ---------------- c1 fp32 [2,256,96,96] -> c1t bf16 [n][100*100][256], pad=2 ----
__global__ __launch_bounds__(256) void k_c1trans(const float* __restrict__ x,
                                                 hbf* __restrict__ c1t) {
    __shared__ float tbuf[32][33];
    const int p0 = blockIdx.x * 32, c0 = blockIdx.y * 32, n = blockIdx.z;
    const int tx = threadIdx.x, ty = threadIdx.y;
#pragma unroll
    for (int i = 0; i < 4; ++i) {
        int ci = c0 + ty * 4 + i;
        tbuf[ty * 4 + i][tx] = x[((size_t)(n * 256 + ci)) * 9216 + p0 + tx];
    }
    __syncthreads();
#pragma unroll
    for (int i = 0; i < 4; ++i) {
        int p = p0 + ty * 4 + i;
        int pp = (p / 96 + 2) * 100 + (p % 96) + 2;
        c1t[((size_t)(n * 10000 + pp)) * 256 + c0 + tx] = __float2bfloat16(tbuf[tx][ty * 4 + i]);
    }
}

// ---------------- small conv weights [64,CI,3,3] fp32 -> [tap][64][CI] bf16 -----
template <int CI>
__global__ __launch_bounds__(256) void k_wtrans_small(const float* __restrict__ w,
                                                      hbf* __restrict__ wt) {
    int idx = blockIdx.x * 256 + threadIdx.x;   // 64*CI
    int co = idx / CI, ci = idx % CI;
    const float* s = w + ((size_t)(co * CI + ci)) * 9;
#pragma unroll
    for (int tap = 0; tap < 9; ++tap)
        wt[((size_t)(tap * 64 + co)) * CI + ci] = __float2bfloat16(s[tap]);
}

// ---------------- dilated 3x3 conv (d=2) MFMA: 64co x 64px tile, split-K by tap row
// Staging lane remap: row = w*16+(l&15), kchunk = l>>4  -> conflict-free frag reads.
template <int CI>
__global__ __launch_bounds__(256) void k_dconv_mfma(const hbf* __restrict__ wt,
                                                    const hbf* __restrict__ it,
                                                    float* __restrict__ accout) {
    __shared__ hbf As[2048];   // 64 rows staged as [wq][16 rows][4 kchunks x 8]
    __shared__ hbf Bs[2048];
    const int tid = threadIdx.x;
    const int l = tid & 63, w = tid >> 6;
    const int P0 = blockIdx.x * 64;
    const int g  = blockIdx.y;
    const int rS = w * 16 + (l & 15);     // staging row
    const int kS = (l >> 4) * 8;          // staging k offset (halves)

    const int p_abs = P0 + rS;
    const int n_i = p_abs / 9216;
    const int pl = p_abs % 9216;
    const hbf* gB = it + ((size_t)(n_i * 10000 + (pl / 96 + 2) * 100 + (pl % 96) + 2)) * CI + kS;

    const int wn = w * 16;
    const int lo = (l & 15) * 8 + (l >> 4) * 128;  // conflict-free fragment offset
    f32x4 acc[4];
#pragma unroll
    for (int i = 0; i < 4; ++i) acc[i] = {0.f, 0.f, 0.f, 0.f};
    hbf* ldsA = As + w * 512;
    hbf* ldsB = Bs + w * 512;

    for (int t = 0; t < 3; ++t) {
        const int tap = g * 3 + t;
        const int dtap = (tap / 3 - 1) * 200 + (tap % 3 - 1) * 2;  // dilation-2 offsets
        const hbf* gA = wt + ((size_t)(tap * 64 + rS)) * CI + kS;
        const hbf* gBt = gB + (ptrdiff_t)dtap * CI;
        for (int k0 = 0; k0 < CI; k0 += 32) {
            __syncthreads();
            __builtin_amdgcn_global_load_lds(
                (const __attribute__((address_space(1))) void*)(gA + k0),
                (__attribute__((address_space(3))) void*)ldsA, 16, 0, 0);
            __builtin_amdgcn_global_load_lds(
                (const __attribute__((address_space(1))) void*)(gBt + k0),
                (__attribute__((address_space(3))) void*)ldsB, 16, 0, 0);
            __syncthreads();
            bf16x8 bfr = *(const bf16x8*)(Bs + w * 512 + lo);
#pragma unroll
            for (int ti = 0; ti < 4; ++ti) {
                bf16x8 af = *(const bf16x8*)(As + ti * 512 + lo);
                acc[ti] = __builtin_amdgcn_mfma_f32_16x16x32_bf16(af, bfr, acc[ti], 0, 0, 0);
            }
        }
    }
    const int px = P0 + wn + (l & 15);
    const int n2 = px / 9216, pl2 = px % 9216;
#pragma unroll
    for (int ti = 0; ti < 4; ++ti) {
        const int mrow = ti * 16 + (l >> 4) * 4;
        float* dst = accout + ((size_t)(n2 * 64 + mrow)) * 9216 + pl2;
#pragma unroll
        for (int r = 0; r < 4; ++r)
            atomicAdd(dst + (size_t)r * 9216, acc[ti][r]);
    }
}

// ---------------- ep_r1: BN+ReLU(r1acc) -> r1t bf16 padded-transposed -----------
__global__ __launch_bounds__(256) void k_ep_r1(const float* __restrict__ acc,
                                               const float* __restrict__ bnp,
                                               hbf* __restrict__ r1t) {
    __shared__ float ss[64], st[64];
    if (threadIdx.x < 64) {
        float s, t; bn_coef(bnp, 64, threadIdx.x, s, t);
        ss[threadIdx.x] = s; st[threadIdx.x] = t;
    }
    __syncthreads();
    const int pi = blockIdx.x * 256 + threadIdx.x;
    const int n = pi / 9216, pl = pi % 9216;
    const int pp = (pl / 96 + 2) * 100 + (pl % 96) + 2;
    hbf* dst = r1t + ((size_t)(n * 10000 + pp)) * 64;
    const float* src = acc + (size_t)n * 64 * 9216 + pl;
#pragma unroll
    for (int co = 0; co < 64; ++co)
        dst[co] = __float2bfloat16(fmaxf(fmaf(src[(size_t)co * 9216], ss[co], st[co]), 0.f));
}

// ---------------- ep_q: elementwise BN+ReLU(qacc) -> q fp32 planar --------------
__global__ void k_ep_q(const float* __restrict__ acc, const float* __restrict__ bnp,
                       float* __restrict__ q) {
    int idx = blockIdx.x * blockDim.x + threadIdx.x;  // 2*64*9216
    int c = (idx / 9216) & 63;
    float s, t; bn_coef(bnp, 64, c, s, t);
    q[idx] = fmaxf(fmaf(acc[idx], s, t), 0.f);
}

// ---------------- 1x1 conv on c2 (512->64), ci split 4-ways, atomic -------------
__global__ __launch_bounds__(192) void k_conv1x1_c2(const float* __restrict__ c2,
                                                    const float* __restrict__ w,
                                                    float* __restrict__ outacc) {
    const int x = threadIdx.x;
    const int y = blockIdx.y * 4 + threadIdx.y;
    const int n = blockIdx.z >> 2;
    const int ci0 = (blockIdx.z & 3) * 128;
    const int cg = blockIdx.x;
    const int p = y * 48 + x;
    float acc[4];
#pragma unroll
    for (int j = 0; j < 4; ++j) acc[j] = 0.f;
    for (int ci = ci0; ci < ci0 + 128; ++ci) {
        float iv = c2[(size_t)(n * 512 + ci) * 2304 + p];
#pragma unroll
        for (int j = 0; j < 4; ++j)
            acc[j] = fmaf(iv, w[(size_t)(cg * 4 + j) * 512 + ci], acc[j]);
    }
#pragma unroll
    for (int j = 0; j < 4; ++j)
        atomicAdd(&outacc[(size_t)(n * 64 + cg * 4 + j) * 2304 + p], acc[j]);
}

// ---------------- bilinear 48->96 (align_corners), optional BN+ReLU -------------
__global__ void k_up96(const float* __restrict__ src, float* __restrict__ dst,
                       int C, const float* __restrict__ bnp) {
    int idx = blockIdx.x * blockDim.x + threadIdx.x;  // 2*C*9216
    int p = idx % 9216;
    int nc = idx / 9216;
    int c = nc % C;
    int y = p / 96, x = p % 96;
    int yn = y * 47, xn = x * 47;
    int y0 = yn / 95, x0 = xn / 95;
    float wy = (float)(yn - y0 * 95) * (1.f / 95.f);
    float wx = (float)(xn - x0 * 95) * (1.f / 95.f);
    int y1 = min(y0 + 1, 47), x1 = min(x0 + 1, 47);
    const float* sp = src + (size_t)nc * 2304;
    float v00 = sp[y0 * 48 + x0], v01 = sp[y0 * 48 + x1];
    float v10 = sp[y1 * 48 + x0], v11 = sp[y1 * 48 + x1];
    float v = (v00 * (1.f - wx) + v01 * wx) * (1.f - wy)
            + (v10 * (1.f - wx) + v11 * wx) * wy;
    if (bnp) {
        float s, t; bn_coef(bnp, C, c, s, t);
        v = fmaxf(fmaf(v, s, t), 0.f);
    }
    dst[idx] = v;
}

// ---------------- energy + softmax -> att [n,9216,9] ---------------------------
__global__ __launch_bounds__(256) void k_attention(const float* __restrict__ q,
                                                   const float* __restrict__ kf,
                                                   float* __restrict__ att) {
    int tid = blockIdx.x * 256 + threadIdx.x;  // 2*9216
    int n = tid / 9216, p = tid % 9216;
    int y = p / 96, x = p % 96;
    float qv[64];
    const float* qb = q + (size_t)n * 64 * 9216 + p;
#pragma unroll
    for (int c = 0; c < 64; ++c) qv[c] = qb[(size_t)c * 9216];
    float e[9];
    const float* kb = kf + (size_t)n * 64 * 9216;
#pragma unroll
    for (int ky = 0; ky < 3; ++ky)
#pragma unroll
        for (int kx = 0; kx < 3; ++kx) {
            int yy = y + 2 * ky - 2, xx = x + 2 * kx - 2;
            float s = 0.f;
            if (yy >= 0 && yy < 96 && xx >= 0 && xx < 96) {
                const float* kp = kb + yy * 96 + xx;
#pragma unroll
                for (int c = 0; c < 64; ++c) s = fmaf(qv[c], kp[(size_t)c * 9216], s);
            }
            e[ky * 3 + kx] = s;
        }
    float m = e[0];
#pragma unroll
    for (int k = 1; k < 9; ++k) m = fmaxf(m, e[k]);
    float sum = 0.f;
#pragma unroll
    for (int k = 0; k < 9; ++k) { e[k] = __expf(e[k] - m); sum += e[k]; }
    float inv = 1.f / sum;
    float* ap = att + (size_t)tid * 9;
#pragma unroll
    for (int k = 0; k < 9; ++k) ap[k] = e[k] * inv;
}

// ---------------- adaptive avg pools s=1,2,3,6 -> pooled [n,2048,50] ------------
__global__ __launch_bounds__(64) void k_pool(const float* __restrict__ xin,
                                             float* __restrict__ pooled) {
    int b = blockIdx.x;            // n*2048+c
    int t = threadIdx.x;
    __shared__ float cells[50];
    if (t < 50) cells[t] = 0.f;
    __syncthreads();
    float rs = 0.f;
    if (t < 48) {
        const float* row = xin + (size_t)b * 2304 + t * 48;
        float s6[6];
#pragma unroll
        for (int j = 0; j < 6; ++j) {
            float s = 0.f;
#pragma unroll
            for (int i = 0; i < 8; ++i) s += row[j * 8 + i];
            s6[j] = s;
        }
        float s3a = s6[0] + s6[1], s3b = s6[2] + s6[3], s3c = s6[4] + s6[5];
        float s2a = s3a + s6[2], s2b = s6[3] + s3c;
        rs = s2a + s2b;
        int r6 = t >> 3, r3 = t >> 4, r2 = t / 24;
        atomicAdd(&cells[14 + r6 * 6 + 0], s6[0]);
        atomicAdd(&cells[14 + r6 * 6 + 1], s6[1]);
        atomicAdd(&cells[14 + r6 * 6 + 2], s6[2]);
        atomicAdd(&cells[14 + r6 * 6 + 3], s6[3]);
        atomicAdd(&cells[14 + r6 * 6 + 4], s6[4]);
        atomicAdd(&cells[14 + r6 * 6 + 5], s6[5]);
        atomicAdd(&cells[5 + r3 * 3 + 0], s3a);
        atomicAdd(&cells[5 + r3 * 3 + 1], s3b);
        atomicAdd(&cells[5 + r3 * 3 + 2], s3c);
        atomicAdd(&cells[1 + r2 * 2 + 0], s2a);
        atomicAdd(&cells[1 + r2 * 2 + 1], s2b);
    }
#pragma unroll
    for (int off = 32; off > 0; off >>= 1) rs += __shfl_down(rs, off);
    if (t == 0) atomicAdd(&cells[0], rs);
    __syncthreads();
    if (t < 50) {
        float inv = (t == 0) ? (1.f / 2304.f)
                  : (t < 5)  ? (1.f / 576.f)
                  : (t < 14) ? (1.f / 256.f)
                             : (1.f / 64.f);
        pooled[(size_t)b * 50 + t] = cells[t] * inv;
    }
}

// ---------------- pconv2: 1x1 conv 2048->512 per cell + BN + ReLU ---------------
__global__ __launch_bounds__(64) void k_pconv2(const float* __restrict__ pooled,
        const float* __restrict__ wp1, const float* __restrict__ bn1,
        const float* __restrict__ wp2, const float* __restrict__ bn2,
        const float* __restrict__ wp3, const float* __restrict__ bn3,
        const float* __restrict__ wp4, const float* __restrict__ bn4,
        float* __restrict__ pconv) {
    const int co = blockIdx.x, n = blockIdx.y;
    const int t = threadIdx.x;
    const int cell = (t < 50) ? t : 49;
    const float* w; const float* bnp;
    if (cell == 0)      { w = wp1; bnp = bn1; }
    else if (cell < 5)  { w = wp2; bnp = bn2; }
    else if (cell < 14) { w = wp3; bnp = bn3; }
    else                { w = wp4; bnp = bn4; }
    const float* pin = pooled + (size_t)n * 2048 * 50 + cell;
    const float* wr = w + (size_t)co * 2048;
    float a = 0.f;
#pragma unroll 4
    for (int c = 0; c < 2048; ++c)
        a = fmaf(pin[(size_t)c * 50], wr[c], a);
    float s, tt; bn_coef(bnp, 512, co, s, tt);
    if (t < 50)
        pconv[((size_t)n * 512 + co) * 50 + cell] = fmaxf(fmaf(a, s, tt), 0.f);
}

// ---------------- w5 fp32 [co][4096][9] psp slice -> wpsp bf16 [tap][b][c][co] --
__global__ __launch_bounds__(256) void k_wpsp_trans(const float* __restrict__ w5,
                                                    hbf* __restrict__ wpsp) {
    const int co = blockIdx.x * 64 + (threadIdx.x & 63);
    const int b = blockIdx.y;
    const int c0 = blockIdx.z * 64 + (threadIdx.x >> 6) * 16;
    for (int i = 0; i < 16; ++i) {
        int c = c0 + i;
        const float* s = w5 + ((size_t)co * 4096 + 2048 + b * 512 + c) * 9;
#pragma unroll
        for (int tap = 0; tap < 9; ++tap)
            wpsp[(((size_t)(tap * 4 + b) * 512) + c) * 512 + co] = __float2bfloat16(s[tap]);
    }
}

// ---------------- computeM2: M[n,co,tap,cell] via coalesced bf16 weights --------
__global__ __launch_bounds__(64) void k_computeM2(const hbf* __restrict__ wpsp,
                                                  const float* __restrict__ pconv,
                                                  float* __restrict__ M) {
    const int cog = blockIdx.x, tap = blockIdx.y;
    const int n = blockIdx.z / 7, chunk = blockIdx.z % 7;
    const int cell0_t[7] = {0, 1, 5, 14, 23, 32, 41};
    const int ncell_t[7] = {1, 4, 9, 9, 9, 9, 9};
    const int btab[7]    = {0, 1, 2, 3, 3, 3, 3};
    const int cell0 = cell0_t[chunk], nc = ncell_t[chunk], b = btab[chunk];
    const int co = cog * 64 + threadIdx.x;
    const hbf* wb = wpsp + ((size_t)(tap * 4 + b) * 512) * 512 + co;
    const float* pc = pconv + (size_t)n * 512 * 50 + cell0;
    float acc[9];
#pragma unroll
    for (int j = 0; j < 9; ++j) acc[j] = 0.f;
    for (int c = 0; c < 512; ++c) {
        float w = __bfloat162float(wb[(size_t)c * 512]);
#pragma unroll
        for (int j = 0; j < 9; ++j)
            acc[j] = fmaf(w, pc[c * 50 + j], acc[j]);
    }
    float* Mp = M + ((size_t)(n * 512 + co) * 9 + tap) * 50 + cell0;
    for (int j = 0; j < nc; ++j) Mp[j] = acc[j];
}

// bilinear cell coefficients for branch with grid s x s at pixel (yy,xx) in 48x48
struct B4 { int c0, c1, c2, c3; float w0, w1, w2, w3; };
__device__ __forceinline__ B4 cell_interp(int yy, int xx, int s, int base) {
    int sm1 = s - 1;
    int yn = yy * sm1, xn = xx * sm1;
    int y0 = yn / 47, x0 = xn / 47;
    float wy = (float)(yn - y0 * 47) * (1.f / 47.f);
    float wx = (float)(xn - x0 * 47) * (1.f / 47.f);
    int y1 = min(y0 + 1, sm1), x1 = min(x0 + 1, sm1);
    B4 r;
    r.c0 = base + y0 * s + x0; r.c1 = base + y0 * s + x1;
    r.c2 = base + y1 * s + x0; r.c3 = base + y1 * s + x1;
    r.w0 = (1.f - wy) * (1.f - wx); r.w1 = (1.f - wy) * wx;
    r.w2 = wy * (1.f - wx);         r.w3 = wy * wx;
    return r;
}

// ---------------- x (fp32 [n,2048,48,48]) -> xtp (bf16 [n,50*50,2048], pad=0) ---
__global__ __launch_bounds__(256) void k_xtrans(const float* __restrict__ x,
                                                hbf* __restrict__ xtp) {
    __shared__ float tbuf[32][33];
    const int p0 = blockIdx.x * 32, c0 = blockIdx.y * 32, n = blockIdx.z;
    const int tx = threadIdx.x, ty = threadIdx.y;
#pragma unroll
    for (int i = 0; i < 4; ++i) {
        int ci = c0 + ty * 4 + i;
        tbuf[ty * 4 + i][tx] = x[((size_t)(n * 2048 + ci)) * 2304 + p0 + tx];
    }
    __syncthreads();
#pragma unroll
    for (int i = 0; i < 4; ++i) {
        int p = p0 + ty * 4 + i;
        int pp = (p / 48 + 1) * 50 + (p % 48) + 1;
        xtp[((size_t)(n * 2500 + pp)) * 2048 + c0 + tx] = __float2bfloat16(tbuf[tx][ty * 4 + i]);
    }
}

// ---------------- w_c5 fp32 [co,4096,9] (ci<2048) -> wt bf16 [tap,co,ci] --------
__global__ __launch_bounds__(256) void k_wtrans(const float* __restrict__ w5,
                                                hbf* __restrict__ wt) {
    int idx = blockIdx.x * 256 + threadIdx.x;   // 512*2048
    int co = idx >> 11, ci = idx & 2047;
    const float* s = w5 + ((size_t)co * 4096 + ci) * 9;
#pragma unroll
    for (int tap = 0; tap < 9; ++tap)
        wt[((size_t)(tap * 512 + co)) * 2048 + ci] = __float2bfloat16(s[tap]);
}

// ---------------- conv5 direct part: MFMA implicit GEMM, split-K per tap --------
// grid(4, 36, 9) block(256). Tile 128co x 128px, BK=32, one tap per z.
// Staging lane remap: row = w*16+(l&15), kchunk = l>>4 -> conflict-free frag reads.
__global__ __launch_bounds__(256) void k_conv5_mfma(const hbf* __restrict__ wt,
                                                    const hbf* __restrict__ xtp,
                                                    float* __restrict__ c5acc) {
    __shared__ hbf As[4096];   // 2 halves x [wq][16 rows][4 kchunks x 8]
    __shared__ hbf Bs[4096];
    const int tid = threadIdx.x;
    const int l = tid & 63, w = tid >> 6;
    const int m0 = blockIdx.x * 128;
    const int P0 = blockIdx.y * 128;
    const int tap = blockIdx.z;
    const int n_img = P0 / 2304;
    const int pbase = P0 - n_img * 2304;
    const int rS = w * 16 + (l & 15);     // staging row within 64-row half
    const int kS = (l >> 4) * 8;          // staging k offset (halves)

    const int p_r0 = pbase + rS;
    const int p_r1 = p_r0 + 64;
    const int dtap = (tap / 3 - 1) * 50 + (tap % 3 - 1);
    const hbf* gA0 = wt + ((size_t)(tap * 512 + m0 + rS)) * 2048 + kS;
    const hbf* gA1 = gA0 + (size_t)64 * 2048;
    const hbf* gB0 = xtp + ((size_t)(n_img * 2500 + p_r0 + 2 * (p_r0 / 48) + 51 + dtap)) * 2048 + kS;
    const hbf* gB1 = xtp + ((size_t)(n_img * 2500 + p_r1 + 2 * (p_r1 / 48) + 51 + dtap)) * 2048 + kS;

    const int wm = (w & 1) * 64, wn = (w >> 1) * 64;
    const int lo = (l & 15) * 8 + (l >> 4) * 128;  // conflict-free fragment offset
    f32x4 acc[4][4];
#pragma unroll
    for (int i = 0; i < 4; ++i)
#pragma unroll
        for (int j = 0; j < 4; ++j) acc[i][j] = {0.f, 0.f, 0.f, 0.f};

    hbf* ldsA0 = As + w * 512;
    hbf* ldsA1 = As + 2048 + w * 512;
    hbf* ldsB0 = Bs + w * 512;
    hbf* ldsB1 = Bs + 2048 + w * 512;

    for (int k0 = 0; k0 < 2048; k0 += 32) {
        __syncthreads();
        __builtin_amdgcn_global_load_lds(
            (const __attribute__((address_space(1))) void*)(gA0 + k0),
            (__attribute__((address_space(3))) void*)ldsA0, 16, 0, 0);
        __builtin_amdgcn_global_load_lds(
            (const __attribute__((address_space(1))) void*)(gA1 + k0),
            (__attribute__((address_space(3))) void*)ldsA1, 16, 0, 0);
        __builtin_amdgcn_global_load_lds(
            (const __attribute__((address_space(1))) void*)(gB0 + k0),
            (__attribute__((address_space(3))) void*)ldsB0, 16, 0, 0);
        __builtin_amdgcn_global_load_lds(
            (const __attribute__((address_space(1))) void*)(gB1 + k0),
            (__attribute__((address_space(3))) void*)ldsB1, 16, 0, 0);
        __syncthreads();
        bf16x8 af[4], bfr[4];
#pragma unroll
        for (int ti = 0; ti < 4; ++ti) {
            const int mb = wm + ti * 16;
            af[ti] = *(const bf16x8*)(As + (mb >> 6) * 2048 + ((mb >> 4) & 3) * 512 + lo);
        }
#pragma unroll
        for (int tj = 0; tj < 4; ++tj) {
            const int nb = wn + tj * 16;
            bfr[tj] = *(const bf16x8*)(Bs + (nb >> 6) * 2048 + ((nb >> 4) & 3) * 512 + lo);
        }
#pragma unroll
        for (int ti = 0; ti < 4; ++ti)
#pragma unroll
            for (int tj = 0; tj < 4; ++tj)
                acc[ti][tj] = __builtin_amdgcn_mfma_f32_16x16x32_bf16(
                    af[ti], bfr[tj], acc[ti][tj], 0, 0, 0);
    }
#pragma unroll
    for (int ti = 0; ti < 4; ++ti) {
        const int mrow = wm + ti * 16 + (l >> 4) * 4;
#pragma unroll
        for (int tj = 0; tj < 4; ++tj) {
            const int p = pbase + wn + tj * 16 + (l & 15);
            float* dst = c5acc + ((size_t)(n_img * 512 + m0 + mrow)) * 2304 + p;
#pragma unroll
            for (int r = 0; r < 4; ++r)
                atomicAdd(dst + (size_t)r * 2304, acc[ti][tj][r]);
        }
    }
}

// ---------------- epilogue: + psp(M)-part, BN, ReLU -> c5out bf16 ---------------
__global__ __launch_bounds__(256) void k_bnrelu_psp(const float* __restrict__ c5acc,
                                                    const float* __restrict__ M,
                                                    const float* __restrict__ bnp,
                                                    hbf* __restrict__ c5out) {
    const int co = blockIdx.x, n = blockIdx.y;
    __shared__ float Ms[450];
    const float* Mrow = M + ((size_t)(n * 512 + co)) * 450;
    for (int i = threadIdx.x; i < 450; i += 256) Ms[i] = Mrow[i];
    __syncthreads();
    float s, t; bn_coef(bnp, 512, co, s, t);
    const size_t base = ((size_t)(n * 512 + co)) * 2304;
#pragma unroll
    for (int i = 0; i < 9; ++i) {
        int p = threadIdx.x + i * 256;
        int y = p / 48, x = p % 48;
        float a = c5acc[base + p];
#pragma unroll
        for (int ky = 0; ky < 3; ++ky) {
            int yy = y + ky - 1;
            if (yy < 0 || yy > 47) continue;
#pragma unroll
            for (int kx = 0; kx < 3; ++kx) {
                int xx = x + kx - 1;
                if (xx < 0 || xx > 47) continue;
                const float* Mp = Ms + (ky * 3 + kx) * 50;
                float sa = Mp[0];
                B4 b2 = cell_interp(yy, xx, 2, 1);
                B4 b3 = cell_interp(yy, xx, 3, 5);
                B4 b6 = cell_interp(yy, xx, 6, 14);
                sa = fmaf(b2.w0, Mp[b2.c0], sa); sa = fmaf(b2.w1, Mp[b2.c1], sa);
                sa = fmaf(b2.w2, Mp[b2.c2], sa); sa = fmaf(b2.w3, Mp[b2.c3], sa);
                sa = fmaf(b3.w0, Mp[b3.c0], sa); sa = fmaf(b3.w1, Mp[b3.c1], sa);
                sa = fmaf(b3.w2, Mp[b3.c2], sa); sa = fmaf(b3.w3, Mp[b3.c3], sa);
                sa = fmaf(b6.w0, Mp[b6.c0], sa); sa = fmaf(b6.w1, Mp[b6.c1], sa);
                sa = fmaf(b6.w2, Mp[b6.c2], sa); sa = fmaf(b6.w3, Mp[b6.c3], sa);
                a += sa;
            }
        }
        c5out[base + p] = __float2bfloat16(fmaxf(fmaf(a, s, t), 0.f));
    }
}

// ---------------- conv6 at 48x48 (512->59, no bias), c5out bf16 -----------------
__global__ __launch_bounds__(192) void k_conv6s(const hbf* __restrict__ c5o,
                                                const float* __restrict__ w,
                                                float* __restrict__ out) {
    const int x = threadIdx.x;
    const int y = blockIdx.y * 4 + threadIdx.y;
    const int n = blockIdx.z;
    const int co = blockIdx.x;
    const int p = y * 48 + x;
    const hbf* ip = c5o + (size_t)n * 512 * 2304 + p;
    const float* wr = w + (size_t)co * 512;
    float a = 0.f;
    for (int ci = 0; ci < 512; ++ci)
        a = fmaf(__bfloat162float(ip[(size_t)ci * 2304]), wr[ci], a);
    out[((size_t)n * 59 + co) * 2304 + p] = a;
}

// ---------------- final: out = bias + sum_k att[k]*c6o[tap_k] -------------------
__global__ void k_final(const float* __restrict__ att, const float* __restrict__ c6o,
                        const float* __restrict__ bias, float* __restrict__ out) {
    int idx = blockIdx.x * blockDim.x + threadIdx.x;  // 2*59*9216
    int p = idx % 9216;
    int nc = idx / 9216;
    int cls = nc % 59, n = nc / 59;
    int y = p / 96, x = p % 96;
    const float* ar = att + ((size_t)n * 9216 + p) * 9;
    const float* cp = c6o + (size_t)nc * 9216;
    float a = bias[cls];
#pragma unroll
    for (int ky = 0; ky < 3; ++ky)
#pragma unroll
        for (int kx = 0; kx < 3; ++kx) {
            int yy = y + 2 * ky - 2, xx = x + 2 * kx - 2;
            if (yy >= 0 && yy < 96 && xx >= 0 && xx < 96)
                a = fmaf(ar[ky * 3 + kx], cp[yy * 96 + xx], a);
        }
    out[idx] = a;
}

extern "C" void kernel_launch(void* const* d_in, const int* in_sizes, int n_in,
                              void* d_out, int out_size, void* d_ws, size_t ws_size,
                              hipStream_t stream) {
    const float* c1    = (const float*)d_in[0];
    const float* c2    = (const float*)d_in[1];
    const float* xin   = (const float*)d_in[2];
    const float* w_r1  = (const float*)d_in[3];
    const float* bn_r1 = (const float*)d_in[4];
    const float* w_r2  = (const float*)d_in[5];
    const float* bn_r2 = (const float*)d_in[6];
    const float* w_r3  = (const float*)d_in[7];
    const float* bn_r3 = (const float*)d_in[8];
    const float* w_p1  = (const float*)d_in[9];
    const float* bn_p1 = (const float*)d_in[10];
    const float* w_p2  = (const float*)d_in[11];
    const float* bn_p2 = (const float*)d_in[12];
    const float* w_p3  = (const float*)d_in[13];
    const float* bn_p3 = (const float*)d_in[14];
    const float* w_p4  = (const float*)d_in[15];
    const float* bn_p4 = (const float*)d_in[16];
    const float* w_c5  = (const float*)d_in[17];
    const float* bn_c5 = (const float*)d_in[18];
    const float* w_c6  = (const float*)d_in[19];
    const float* b_c6  = (const float*)d_in[20];
    float* out = (float*)d_out;
    (void)in_sizes; (void)n_in; (void)out_size; (void)ws_size;

    char* base = (char*)d_ws;
    float* att = (float*)base;                    // 663,552 B
    char*  A   = base + 663552;
    // ---- phase 1 layout (region A) ----
    hbf*   c1t   = (hbf*)A;                       // 10,240,000
    hbf*   r1t   = (hbf*)(A + 10240000);          //  2,560,000
    float* r1acc = (float*)(A + 12800000);        //  4,718,592
    float* qacc  = (float*)(A + 17518592);        //  4,718,592
    float* c2acc = (float*)(A + 22237184);        //  1,179,648  (fill ends 23,416,832)
    float* q     = (float*)(A + 23416832);        //  4,718,592
    float* c2r   = (float*)(A + 28135424);        //  4,718,592
    hbf*   wr1t  = (hbf*)(A + 32854016);          //    294,912
    hbf*   wr2t  = (hbf*)(A + 33148928);          //     73,728  (ends 33,222,656)
    // ---- phase 2 early (region A): wpsp aliased under xtp, consumed pre-fill ----
    hbf*   wpsp   = (hbf*)A;                      // 18,874,368 (< xtp's 20,480,000)
    float* pooled = (float*)(A + 48791552);       //    819,200
    float* pconv  = (float*)(A + 49610752);       //    204,800
    float* M      = (float*)(A + 49815552);       //  1,843,200  (ends 51,658,752)
    // ---- phase 2 main (region A, reuses wpsp space) ----
    hbf*   xtp    = (hbf*)A;                      // 20,480,000
    float* c5acc  = (float*)(A + 20480000);       //  9,437,184
    hbf*   wt     = (hbf*)(A + 29917184);         // 18,874,368
    // ---- phase 2b (after conv5), aliased over xtp ----
    hbf*   c5out = (hbf*)A;                       //  4,718,592
    float* c6s   = (float*)(A + 4718592);         //  1,087,488
    float* c6o   = (float*)(A + 5806080);         //  4,349,952  (ends 10,156,032)
    // total ws: 663,552 + 51,658,752 = 52,322,304 B (unchanged)

    // ---- phase 1: attention branch ----
    k_fill0<<<dim3(22868), 256, 0, stream>>>((uint32_t*)A, 5854208);
    k_c1trans<<<dim3(288, 8, 2), dim3(32, 8), 0, stream>>>(c1, c1t);
    k_wtrans_small<256><<<dim3(64), 256, 0, stream>>>(w_r1, wr1t);
    k_wtrans_small<64><<<dim3(16), 256, 0, stream>>>(w_r2, wr2t);
    k_dconv_mfma<256><<<dim3(288, 3), 256, 0, stream>>>(wr1t, c1t, r1acc);
    k_ep_r1<<<dim3(72), 256, 0, stream>>>(r1acc, bn_r1, r1t);
    k_dconv_mfma<64><<<dim3(288, 3), 256, 0, stream>>>(wr2t, r1t, qacc);
    k_ep_q<<<dim3(4608), 256, 0, stream>>>(qacc, bn_r2, q);
    k_conv1x1_c2<<<dim3(16, 12, 8), dim3(48, 4), 0, stream>>>(c2, w_r3, c2acc);
    k_up96<<<dim3(2 * 64 * 9216 / 256), 256, 0, stream>>>(c2acc, c2r, 64, bn_r3);
    k_attention<<<dim3(2 * 9216 / 256), 256, 0, stream>>>(q, c2r, att);
    // ---- phase 2: psp branch ----
    k_pool<<<dim3(4096), 64, 0, stream>>>(xin, pooled);
    k_pconv2<<<dim3(512, 2), 64, 0, stream>>>(pooled, w_p1, bn_p1, w_p2, bn_p2,
                                              w_p3, bn_p3, w_p4, bn_p4, pconv);
    k_wpsp_trans<<<dim3(8, 4, 8), 256, 0, stream>>>(w_c5, wpsp);
    k_computeM2<<<dim3(8, 9, 14), 64, 0, stream>>>(wpsp, pconv, M);
    k_fill0<<<dim3(29216), 256, 0, stream>>>((uint32_t*)xtp, 7479296);
    k_xtrans<<<dim3(72, 64, 2), dim3(32, 8), 0, stream>>>(xin, xtp);
    k_wtrans<<<dim3(4096), 256, 0, stream>>>(w_c5, wt);
    k_conv5_mfma<<<dim3(4, 36, 9), 256, 0, stream>>>(wt, xtp, c5acc);
    k_bnrelu_psp<<<dim3(512, 2), 256, 0, stream>>>(c5acc, M, bn_c5, c5out);
    // classifier (conv6 commuted before upsample) + attention aggregation
    k_conv6s<<<dim3(59, 12, 2), dim3(48, 4), 0, stream>>>(c5out, w_c6, c6s);
    k_up96<<<dim3(2 * 59 * 9216 / 256), 256, 0, stream>>>(c6s, c6o, 59, nullptr);
    k_final<<<dim3(2 * 59 * 9216 / 256), 256, 0, stream>>>(att, c6o, b_c6, out);
}

// Round 7
// 926.802 us; speedup vs baseline: 1.0828x; 1.0828x over previous
//
#include <hip/hip_runtime.h>
#include <hip/hip_bf16.h>
#include <cstddef>
#include <cstdint>

typedef __hip_bfloat16 hbf;
typedef __bf16 bf16x8 __attribute__((ext_vector_type(8)));
typedef float f32x4 __attribute__((ext_vector_type(4)));

// bn: y = x*s + t, s = g*rsqrt(v+eps), t = b - m*s
__device__ __forceinline__ void bn_coef(const float* __restrict__ p, int C, int c,
                                        float& s, float& t) {
    float g = p[c];
    float b = p[C + c];
    float m = p[2 * C + c];
    float v = p[3 * C + c];
    s = g * rsqrtf(v + 1e-5f);
    t = b - m * s;
}

// ---------------- zero-fill (dwords) --------------------------------------------
__global__ void k_fill0(uint32_t* __restrict__ p, int n) {
    int i = blockIdx.x * blockDim.x + threadIdx.x;
    if (i < n) p[i] = 0u;
}

// ---------------- c1 fp32 [2,256,96,96] -> c1t bf16 [n][100*100][256], pad=2 ----
__global__ __launch_bounds__(256) void k_c1trans(const float* __restrict__ x,
                                                 hbf* __restrict__ c1t) {
    __shared__ float tbuf[32][33];
    const int p0 = blockIdx.x * 32, c0 = blockIdx.y * 32, n = blockIdx.z;
    const int tx = threadIdx.x, ty = threadIdx.y;
#pragma unroll
    for (int i = 0; i < 4; ++i) {
        int ci = c0 + ty * 4 + i;
        tbuf[ty * 4 + i][tx] = x[((size_t)(n * 256 + ci)) * 9216 + p0 + tx];
    }
    __syncthreads();
#pragma unroll
    for (int i = 0; i < 4; ++i) {
        int p = p0 + ty * 4 + i;
        int pp = (p / 96 + 2) * 100 + (p % 96) + 2;
        c1t[((size_t)(n * 10000 + pp)) * 256 + c0 + tx] = __float2bfloat16(tbuf[tx][ty * 4 + i]);
    }
}

// ---------------- small conv weights [64,CI,3,3] fp32 -> [tap][64][CI] bf16 -----
template <int CI>
__global__ __launch_bounds__(256) void k_wtrans_small(const float* __restrict__ w,
                                                      hbf* __restrict__ wt) {
    int idx = blockIdx.x * 256 + threadIdx.x;   // 64*CI
    int co = idx / CI, ci = idx % CI;
    const float* s = w + ((size_t)(co * CI + ci)) * 9;
#pragma unroll
    for (int tap = 0; tap < 9; ++tap)
        wt[((size_t)(tap * 64 + co)) * CI + ci] = __float2bfloat16(s[tap]);
}

// ---------------- dilated 3x3 conv (d=2) MFMA: 64co x 64px tile, split-K by tap row
// Staging lane remap: row = w*16+(l&15), kchunk = l>>4  -> conflict-free frag reads.
template <int CI>
__global__ __launch_bounds__(256) void k_dconv_mfma(const hbf* __restrict__ wt,
                                                    const hbf* __restrict__ it,
                                                    float* __restrict__ accout) {
    __shared__ hbf As[2048];   // 64 rows staged as [wq][16 rows][4 kchunks x 8]
    __shared__ hbf Bs[2048];
    const int tid = threadIdx.x;
    const int l = tid & 63, w = tid >> 6;
    const int P0 = blockIdx.x * 64;
    const int g  = blockIdx.y;
    const int rS = w * 16 + (l & 15);     // staging row
    const int kS = (l >> 4) * 8;          // staging k offset (halves)

    const int p_abs = P0 + rS;
    const int n_i = p_abs / 9216;
    const int pl = p_abs % 9216;
    const hbf* gB = it + ((size_t)(n_i * 10000 + (pl / 96 + 2) * 100 + (pl % 96) + 2)) * CI + kS;

    const int wn = w * 16;
    const int lo = (l & 15) * 8 + (l >> 4) * 128;  // conflict-free fragment offset
    f32x4 acc[4];
#pragma unroll
    for (int i = 0; i < 4; ++i) acc[i] = {0.f, 0.f, 0.f, 0.f};
    hbf* ldsA = As + w * 512;
    hbf* ldsB = Bs + w * 512;

    for (int t = 0; t < 3; ++t) {
        const int tap = g * 3 + t;
        const int dtap = (tap / 3 - 1) * 200 + (tap % 3 - 1) * 2;  // dilation-2 offsets
        const hbf* gA = wt + ((size_t)(tap * 64 + rS)) * CI + kS;
        const hbf* gBt = gB + (ptrdiff_t)dtap * CI;
        for (int k0 = 0; k0 < CI; k0 += 32) {
            __syncthreads();
            __builtin_amdgcn_global_load_lds(
                (const __attribute__((address_space(1))) void*)(gA + k0),
                (__attribute__((address_space(3))) void*)ldsA, 16, 0, 0);
            __builtin_amdgcn_global_load_lds(
                (const __attribute__((address_space(1))) void*)(gBt + k0),
                (__attribute__((address_space(3))) void*)ldsB, 16, 0, 0);
            __syncthreads();
            bf16x8 bfr = *(const bf16x8*)(Bs + w * 512 + lo);
#pragma unroll
            for (int ti = 0; ti < 4; ++ti) {
                bf16x8 af = *(const bf16x8*)(As + ti * 512 + lo);
                acc[ti] = __builtin_amdgcn_mfma_f32_16x16x32_bf16(af, bfr, acc[ti], 0, 0, 0);
            }
        }
    }
    const int px = P0 + wn + (l & 15);
    const int n2 = px / 9216, pl2 = px % 9216;
#pragma unroll
    for (int ti = 0; ti < 4; ++ti) {
        const int mrow = ti * 16 + (l >> 4) * 4;
        float* dst = accout + ((size_t)(n2 * 64 + mrow)) * 9216 + pl2;
#pragma unroll
        for (int r = 0; r < 4; ++r)
            atomicAdd(dst + (size_t)r * 9216, acc[ti][r]);
    }
}

// ---------------- ep_r1: BN+ReLU(r1acc) -> r1t bf16 padded-transposed -----------
__global__ __launch_bounds__(256) void k_ep_r1(const float* __restrict__ acc,
                                               const float* __restrict__ bnp,
                                               hbf* __restrict__ r1t) {
    __shared__ float ss[64], st[64];
    if (threadIdx.x < 64) {
        float s, t; bn_coef(bnp, 64, threadIdx.x, s, t);
        ss[threadIdx.x] = s; st[threadIdx.x] = t;
    }
    __syncthreads();
    const int pi = blockIdx.x * 256 + threadIdx.x;
    const int n = pi / 9216, pl = pi % 9216;
    const int pp = (pl / 96 + 2) * 100 + (pl % 96) + 2;
    hbf* dst = r1t + ((size_t)(n * 10000 + pp)) * 64;
    const float* src = acc + (size_t)n * 64 * 9216 + pl;
#pragma unroll
    for (int co = 0; co < 64; ++co)
        dst[co] = __float2bfloat16(fmaxf(fmaf(src[(size_t)co * 9216], ss[co], st[co]), 0.f));
}

// ---------------- ep_q: elementwise BN+ReLU(qacc) -> q fp32 planar --------------
__global__ void k_ep_q(const float* __restrict__ acc, const float* __restrict__ bnp,
                       float* __restrict__ q) {
    int idx = blockIdx.x * blockDim.x + threadIdx.x;  // 2*64*9216
    int c = (idx / 9216) & 63;
    float s, t; bn_coef(bnp, 64, c, s, t);
    q[idx] = fmaxf(fmaf(acc[idx], s, t), 0.f);
}

// ---------------- 1x1 conv on c2 (512->64), ci split 4-ways, atomic -------------
__global__ __launch_bounds__(192) void k_conv1x1_c2(const float* __restrict__ c2,
                                                    const float* __restrict__ w,
                                                    float* __restrict__ outacc) {
    const int x = threadIdx.x;
    const int y = blockIdx.y * 4 + threadIdx.y;
    const int n = blockIdx.z >> 2;
    const int ci0 = (blockIdx.z & 3) * 128;
    const int cg = blockIdx.x;
    const int p = y * 48 + x;
    float acc[4];
#pragma unroll
    for (int j = 0; j < 4; ++j) acc[j] = 0.f;
    for (int ci = ci0; ci < ci0 + 128; ++ci) {
        float iv = c2[(size_t)(n * 512 + ci) * 2304 + p];
#pragma unroll
        for (int j = 0; j < 4; ++j)
            acc[j] = fmaf(iv, w[(size_t)(cg * 4 + j) * 512 + ci], acc[j]);
    }
#pragma unroll
    for (int j = 0; j < 4; ++j)
        atomicAdd(&outacc[(size_t)(n * 64 + cg * 4 + j) * 2304 + p], acc[j]);
}

// ---------------- bilinear 48->96 (align_corners), optional BN+ReLU -------------
__global__ void k_up96(const float* __restrict__ src, float* __restrict__ dst,
                       int C, const float* __restrict__ bnp) {
    int idx = blockIdx.x * blockDim.x + threadIdx.x;  // 2*C*9216
    int p = idx % 9216;
    int nc = idx / 9216;
    int c = nc % C;
    int y = p / 96, x = p % 96;
    int yn = y * 47, xn = x * 47;
    int y0 = yn / 95, x0 = xn / 95;
    float wy = (float)(yn - y0 * 95) * (1.f / 95.f);
    float wx = (float)(xn - x0 * 95) * (1.f / 95.f);
    int y1 = min(y0 + 1, 47), x1 = min(x0 + 1, 47);
    const float* sp = src + (size_t)nc * 2304;
    float v00 = sp[y0 * 48 + x0], v01 = sp[y0 * 48 + x1];
    float v10 = sp[y1 * 48 + x0], v11 = sp[y1 * 48 + x1];
    float v = (v00 * (1.f - wx) + v01 * wx) * (1.f - wy)
            + (v10 * (1.f - wx) + v11 * wx) * wy;
    if (bnp) {
        float s, t; bn_coef(bnp, C, c, s, t);
        v = fmaxf(fmaf(v, s, t), 0.f);
    }
    dst[idx] = v;
}

// ---------------- energy + softmax -> att [n,9216,9] ---------------------------
__global__ __launch_bounds__(256) void k_attention(const float* __restrict__ q,
                                                   const float* __restrict__ kf,
                                                   float* __restrict__ att) {
    int tid = blockIdx.x * 256 + threadIdx.x;  // 2*9216
    int n = tid / 9216, p = tid % 9216;
    int y = p / 96, x = p % 96;
    float qv[64];
    const float* qb = q + (size_t)n * 64 * 9216 + p;
#pragma unroll
    for (int c = 0; c < 64; ++c) qv[c] = qb[(size_t)c * 9216];
    float e[9];
    const float* kb = kf + (size_t)n * 64 * 9216;
#pragma unroll
    for (int ky = 0; ky < 3; ++ky)
#pragma unroll
        for (int kx = 0; kx < 3; ++kx) {
            int yy = y + 2 * ky - 2, xx = x + 2 * kx - 2;
            float s = 0.f;
            if (yy >= 0 && yy < 96 && xx >= 0 && xx < 96) {
                const float* kp = kb + yy * 96 + xx;
#pragma unroll
                for (int c = 0; c < 64; ++c) s = fmaf(qv[c], kp[(size_t)c * 9216], s);
            }
            e[ky * 3 + kx] = s;
        }
    float m = e[0];
#pragma unroll
    for (int k = 1; k < 9; ++k) m = fmaxf(m, e[k]);
    float sum = 0.f;
#pragma unroll
    for (int k = 0; k < 9; ++k) { e[k] = __expf(e[k] - m); sum += e[k]; }
    float inv = 1.f / sum;
    float* ap = att + (size_t)tid * 9;
#pragma unroll
    for (int k = 0; k < 9; ++k) ap[k] = e[k] * inv;
}

// ---------------- adaptive avg pools s=1,2,3,6 -> pooled [n,2048,50] ------------
__global__ __launch_bounds__(64) void k_pool(const float* __restrict__ xin,
                                             float* __restrict__ pooled) {
    int b = blockIdx.x;            // n*2048+c
    int t = threadIdx.x;
    __shared__ float cells[50];
    if (t < 50) cells[t] = 0.f;
    __syncthreads();
    float rs = 0.f;
    if (t < 48) {
        const float* row = xin + (size_t)b * 2304 + t * 48;
        float s6[6];
#pragma unroll
        for (int j = 0; j < 6; ++j) {
            float s = 0.f;
#pragma unroll
            for (int i = 0; i < 8; ++i) s += row[j * 8 + i];
            s6[j] = s;
        }
        float s3a = s6[0] + s6[1], s3b = s6[2] + s6[3], s3c = s6[4] + s6[5];
        float s2a = s3a + s6[2], s2b = s6[3] + s3c;
        rs = s2a + s2b;
        int r6 = t >> 3, r3 = t >> 4, r2 = t / 24;
        atomicAdd(&cells[14 + r6 * 6 + 0], s6[0]);
        atomicAdd(&cells[14 + r6 * 6 + 1], s6[1]);
        atomicAdd(&cells[14 + r6 * 6 + 2], s6[2]);
        atomicAdd(&cells[14 + r6 * 6 + 3], s6[3]);
        atomicAdd(&cells[14 + r6 * 6 + 4], s6[4]);
        atomicAdd(&cells[14 + r6 * 6 + 5], s6[5]);
        atomicAdd(&cells[5 + r3 * 3 + 0], s3a);
        atomicAdd(&cells[5 + r3 * 3 + 1], s3b);
        atomicAdd(&cells[5 + r3 * 3 + 2], s3c);
        atomicAdd(&cells[1 + r2 * 2 + 0], s2a);
        atomicAdd(&cells[1 + r2 * 2 + 1], s2b);
    }
#pragma unroll
    for (int off = 32; off > 0; off >>= 1) rs += __shfl_down(rs, off);
    if (t == 0) atomicAdd(&cells[0], rs);
    __syncthreads();
    if (t < 50) {
        float inv = (t == 0) ? (1.f / 2304.f)
                  : (t < 5)  ? (1.f / 576.f)
                  : (t < 14) ? (1.f / 256.f)
                             : (1.f / 64.f);
        pooled[(size_t)b * 50 + t] = cells[t] * inv;
    }
}

// ---------------- pconv2: 1x1 conv 2048->512 per cell + BN + ReLU ---------------
__global__ __launch_bounds__(64) void k_pconv2(const float* __restrict__ pooled,
        const float* __restrict__ wp1, const float* __restrict__ bn1,
        const float* __restrict__ wp2, const float* __restrict__ bn2,
        const float* __restrict__ wp3, const float* __restrict__ bn3,
        const float* __restrict__ wp4, const float* __restrict__ bn4,
        float* __restrict__ pconv) {
    const int co = blockIdx.x, n = blockIdx.y;
    const int t = threadIdx.x;
    const int cell = (t < 50) ? t : 49;
    const float* w; const float* bnp;
    if (cell == 0)      { w = wp1; bnp = bn1; }
    else if (cell < 5)  { w = wp2; bnp = bn2; }
    else if (cell < 14) { w = wp3; bnp = bn3; }
    else                { w = wp4; bnp = bn4; }
    const float* pin = pooled + (size_t)n * 2048 * 50 + cell;
    const float* wr = w + (size_t)co * 2048;
    float a = 0.f;
#pragma unroll 4
    for (int c = 0; c < 2048; ++c)
        a = fmaf(pin[(size_t)c * 50], wr[c], a);
    float s, tt; bn_coef(bnp, 512, co, s, tt);
    if (t < 50)
        pconv[((size_t)n * 512 + co) * 50 + cell] = fmaxf(fmaf(a, s, tt), 0.f);
}

// ---------------- w5 fp32 [co][4096][9] psp slice -> wpsp bf16 [tap][b][c][co] --
__global__ __launch_bounds__(256) void k_wpsp_trans(const float* __restrict__ w5,
                                                    hbf* __restrict__ wpsp) {
    const int co = blockIdx.x * 64 + (threadIdx.x & 63);
    const int b = blockIdx.y;
    const int c0 = blockIdx.z * 64 + (threadIdx.x >> 6) * 16;
    for (int i = 0; i < 16; ++i) {
        int c = c0 + i;
        const float* s = w5 + ((size_t)co * 4096 + 2048 + b * 512 + c) * 9;
#pragma unroll
        for (int tap = 0; tap < 9; ++tap)
            wpsp[(((size_t)(tap * 4 + b) * 512) + c) * 512 + co] = __float2bfloat16(s[tap]);
    }
}

// ---------------- computeM2: M[n,co,tap,cell] via coalesced bf16 weights --------
__global__ __launch_bounds__(64) void k_computeM2(const hbf* __restrict__ wpsp,
                                                  const float* __restrict__ pconv,
                                                  float* __restrict__ M) {
    const int cog = blockIdx.x, tap = blockIdx.y;
    const int n = blockIdx.z / 7, chunk = blockIdx.z % 7;
    const int cell0_t[7] = {0, 1, 5, 14, 23, 32, 41};
    const int ncell_t[7] = {1, 4, 9, 9, 9, 9, 9};
    const int btab[7]    = {0, 1, 2, 3, 3, 3, 3};
    const int cell0 = cell0_t[chunk], nc = ncell_t[chunk], b = btab[chunk];
    const int co = cog * 64 + threadIdx.x;
    const hbf* wb = wpsp + ((size_t)(tap * 4 + b) * 512) * 512 + co;
    const float* pc = pconv + (size_t)n * 512 * 50 + cell0;
    float acc[9];
#pragma unroll
    for (int j = 0; j < 9; ++j) acc[j] = 0.f;
    for (int c = 0; c < 512; ++c) {
        float w = __bfloat162float(wb[(size_t)c * 512]);
#pragma unroll
        for (int j = 0; j < 9; ++j)
            acc[j] = fmaf(w, pc[c * 50 + j], acc[j]);
    }
    float* Mp = M + ((size_t)(n * 512 + co) * 9 + tap) * 50 + cell0;
    for (int j = 0; j < nc; ++j) Mp[j] = acc[j];
}

// bilinear cell coefficients for branch with grid s x s at pixel (yy,xx) in 48x48
struct B4 { int c0, c1, c2, c3; float w0, w1, w2, w3; };
__device__ __forceinline__ B4 cell_interp(int yy, int xx, int s, int base) {
    int sm1 = s - 1;
    int yn = yy * sm1, xn = xx * sm1;
    int y0 = yn / 47, x0 = xn / 47;
    float wy = (float)(yn - y0 * 47) * (1.f / 47.f);
    float wx = (float)(xn - x0 * 47) * (1.f / 47.f);
    int y1 = min(y0 + 1, sm1), x1 = min(x0 + 1, sm1);
    B4 r;
    r.c0 = base + y0 * s + x0; r.c1 = base + y0 * s + x1;
    r.c2 = base + y1 * s + x0; r.c3 = base + y1 * s + x1;
    r.w0 = (1.f - wy) * (1.f - wx); r.w1 = (1.f - wy) * wx;
    r.w2 = wy * (1.f - wx);         r.w3 = wy * wx;
    return r;
}

// ---------------- x (fp32 [n,2048,48,48]) -> xtp (bf16 [n,50*50,2048], pad=0) ---
__global__ __launch_bounds__(256) void k_xtrans(const float* __restrict__ x,
                                                hbf* __restrict__ xtp) {
    __shared__ float tbuf[32][33];
    const int p0 = blockIdx.x * 32, c0 = blockIdx.y * 32, n = blockIdx.z;
    const int tx = threadIdx.x, ty = threadIdx.y;
#pragma unroll
    for (int i = 0; i < 4; ++i) {
        int ci = c0 + ty * 4 + i;
        tbuf[ty * 4 + i][tx] = x[((size_t)(n * 2048 + ci)) * 2304 + p0 + tx];
    }
    __syncthreads();
#pragma unroll
    for (int i = 0; i < 4; ++i) {
        int p = p0 + ty * 4 + i;
        int pp = (p / 48 + 1) * 50 + (p % 48) + 1;
        xtp[((size_t)(n * 2500 + pp)) * 2048 + c0 + tx] = __float2bfloat16(tbuf[tx][ty * 4 + i]);
    }
}

// ---------------- w_c5 fp32 [co,4096,9] (ci<2048) -> wt bf16 [tap,co,ci] --------
__global__ __launch_bounds__(256) void k_wtrans(const float* __restrict__ w5,
                                                hbf* __restrict__ wt) {
    int idx = blockIdx.x * 256 + threadIdx.x;   // 512*2048
    int co = idx >> 11, ci = idx & 2047;
    const float* s = w5 + ((size_t)co * 4096 + ci) * 9;
#pragma unroll
    for (int tap = 0; tap < 9; ++tap)
        wt[((size_t)(tap * 512 + co)) * 2048 + ci] = __float2bfloat16(s[tap]);
}

// ---------------- conv5 direct part: MFMA implicit GEMM, split-K by tap group ---
// grid(4, 36, 3) block(256). Tile 128co x 128px, BK=32, taps g*3..g*3+2.
// Staging lane remap: row = w*16+(l&15), kchunk = l>>4 -> conflict-free frag reads.
__global__ __launch_bounds__(256) void k_conv5_mfma(const hbf* __restrict__ wt,
                                                    const hbf* __restrict__ xtp,
                                                    float* __restrict__ c5acc) {
    __shared__ hbf As[4096];   // 2 halves x [wq][16 rows][4 kchunks x 8]
    __shared__ hbf Bs[4096];
    const int tid = threadIdx.x;
    const int l = tid & 63, w = tid >> 6;
    const int m0 = blockIdx.x * 128;
    const int P0 = blockIdx.y * 128;
    const int g  = blockIdx.z;
    const int n_img = P0 / 2304;
    const int pbase = P0 - n_img * 2304;
    const int rS = w * 16 + (l & 15);     // staging row within 64-row half
    const int kS = (l >> 4) * 8;          // staging k offset (halves)

    const int p_r0 = pbase + rS;
    const int p_r1 = p_r0 + 64;
    const size_t bB0 = ((size_t)(n_img * 2500 + p_r0 + 2 * (p_r0 / 48) + 51)) * 2048 + kS;
    const size_t bB1 = ((size_t)(n_img * 2500 + p_r1 + 2 * (p_r1 / 48) + 51)) * 2048 + kS;

    const int wm = (w & 1) * 64, wn = (w >> 1) * 64;
    const int lo = (l & 15) * 8 + (l >> 4) * 128;  // conflict-free fragment offset
    f32x4 acc[4][4];
#pragma unroll
    for (int i = 0; i < 4; ++i)
#pragma unroll
        for (int j = 0; j < 4; ++j) acc[i][j] = {0.f, 0.f, 0.f, 0.f};

    hbf* ldsA0 = As + w * 512;
    hbf* ldsA1 = As + 2048 + w * 512;
    hbf* ldsB0 = Bs + w * 512;
    hbf* ldsB1 = Bs + 2048 + w * 512;

    for (int t = 0; t < 3; ++t) {
        const int tap = g * 3 + t;
        const int dtap = (tap / 3 - 1) * 50 + (tap % 3 - 1);
        const hbf* gA0 = wt + ((size_t)(tap * 512 + m0 + rS)) * 2048 + kS;
        const hbf* gA1 = gA0 + (size_t)64 * 2048;
        const hbf* gB0 = xtp + bB0 + (ptrdiff_t)dtap * 2048;
        const hbf* gB1 = xtp + bB1 + (ptrdiff_t)dtap * 2048;
        for (int k0 = 0; k0 < 2048; k0 += 32) {
            __syncthreads();
            __builtin_amdgcn_global_load_lds(
                (const __attribute__((address_space(1))) void*)(gA0 + k0),
                (__attribute__((address_space(3))) void*)ldsA0, 16, 0, 0);
            __builtin_amdgcn_global_load_lds(
                (const __attribute__((address_space(1))) void*)(gA1 + k0),
                (__attribute__((address_space(3))) void*)ldsA1, 16, 0, 0);
            __builtin_amdgcn_global_load_lds(
                (const __attribute__((address_space(1))) void*)(gB0 + k0),
                (__attribute__((address_space(3))) void*)ldsB0, 16, 0, 0);
            __builtin_amdgcn_global_load_lds(
                (const __attribute__((address_space(1))) void*)(gB1 + k0),
                (__attribute__((address_space(3))) void*)ldsB1, 16, 0, 0);
            __syncthreads();
            bf16x8 af[4], bfr[4];
#pragma unroll
            for (int ti = 0; ti < 4; ++ti) {
                const int mb = wm + ti * 16;
                af[ti] = *(const bf16x8*)(As + (mb >> 6) * 2048 + ((mb >> 4) & 3) * 512 + lo);
            }
#pragma unroll
            for (int tj = 0; tj < 4; ++tj) {
                const int nb = wn + tj * 16;
                bfr[tj] = *(const bf16x8*)(Bs + (nb >> 6) * 2048 + ((nb >> 4) & 3) * 512 + lo);
            }
#pragma unroll
            for (int ti = 0; ti < 4; ++ti)
#pragma unroll
                for (int tj = 0; tj < 4; ++tj)
                    acc[ti][tj] = __builtin_amdgcn_mfma_f32_16x16x32_bf16(
                        af[ti], bfr[tj], acc[ti][tj], 0, 0, 0);
        }
    }
#pragma unroll
    for (int ti = 0; ti < 4; ++ti) {
        const int mrow = wm + ti * 16 + (l >> 4) * 4;
#pragma unroll
        for (int tj = 0; tj < 4; ++tj) {
            const int p = pbase + wn + tj * 16 + (l & 15);
            float* dst = c5acc + ((size_t)(n_img * 512 + m0 + mrow)) * 2304 + p;
#pragma unroll
            for (int r = 0; r < 4; ++r)
                atomicAdd(dst + (size_t)r * 2304, acc[ti][tj][r]);
        }
    }
}

// ---------------- epilogue: + psp(M)-part, BN, ReLU -> c5out bf16 ---------------
__global__ __launch_bounds__(256) void k_bnrelu_psp(const float* __restrict__ c5acc,
                                                    const float* __restrict__ M,
                                                    const float* __restrict__ bnp,
                                                    hbf* __restrict__ c5out) {
    const int co = blockIdx.x, n = blockIdx.y;
    __shared__ float Ms[450];
    const float* Mrow = M + ((size_t)(n * 512 + co)) * 450;
    for (int i = threadIdx.x; i < 450; i += 256) Ms[i] = Mrow[i];
    __syncthreads();
    float s, t; bn_coef(bnp, 512, co, s, t);
    const size_t base = ((size_t)(n * 512 + co)) * 2304;
#pragma unroll
    for (int i = 0; i < 9; ++i) {
        int p = threadIdx.x + i * 256;
        int y = p / 48, x = p % 48;
        float a = c5acc[base + p];
#pragma unroll
        for (int ky = 0; ky < 3; ++ky) {
            int yy = y + ky - 1;
            if (yy < 0 || yy > 47) continue;
#pragma unroll
            for (int kx = 0; kx < 3; ++kx) {
                int xx = x + kx - 1;
                if (xx < 0 || xx > 47) continue;
                const float* Mp = Ms + (ky * 3 + kx) * 50;
                float sa = Mp[0];
                B4 b2 = cell_interp(yy, xx, 2, 1);
                B4 b3 = cell_interp(yy, xx, 3, 5);
                B4 b6 = cell_interp(yy, xx, 6, 14);
                sa = fmaf(b2.w0, Mp[b2.c0], sa); sa = fmaf(b2.w1, Mp[b2.c1], sa);
                sa = fmaf(b2.w2, Mp[b2.c2], sa); sa = fmaf(b2.w3, Mp[b2.c3], sa);
                sa = fmaf(b3.w0, Mp[b3.c0], sa); sa = fmaf(b3.w1, Mp[b3.c1], sa);
                sa = fmaf(b3.w2, Mp[b3.c2], sa); sa = fmaf(b3.w3, Mp[b3.c3], sa);
                sa = fmaf(b6.w0, Mp[b6.c0], sa); sa = fmaf(b6.w1, Mp[b6.c1], sa);
                sa = fmaf(b6.w2, Mp[b6.c2], sa); sa = fmaf(b6.w3, Mp[b6.c3], sa);
                a += sa;
            }
        }
        c5out[base + p] = __float2bfloat16(fmaxf(fmaf(a, s, t), 0.f));
    }
}

// ---------------- conv6 at 48x48 (512->59, no bias), c5out bf16 -----------------
__global__ __launch_bounds__(192) void k_conv6s(const hbf* __restrict__ c5o,
                                                const float* __restrict__ w,
                                                float* __restrict__ out) {
    const int x = threadIdx.x;
    const int y = blockIdx.y * 4 + threadIdx.y;
    const int n = blockIdx.z;
    const int co = blockIdx.x;
    const int p = y * 48 + x;
    const hbf* ip = c5o + (size_t)n * 512 * 2304 + p;
    const float* wr = w + (size_t)co * 512;
    float a = 0.f;
    for (int ci = 0; ci < 512; ++ci)
        a = fmaf(__bfloat162float(ip[(size_t)ci * 2304]), wr[ci], a);
    out[((size_t)n * 59 + co) * 2304 + p] = a;
}

// ---------------- final: out = bias + sum_k att[k]*c6o[tap_k] -------------------
__global__ void k_final(const float* __restrict__ att, const float* __restrict__ c6o,
                        const float* __restrict__ bias, float* __restrict__ out) {
    int idx = blockIdx.x * blockDim.x + threadIdx.x;  // 2*59*9216
    int p = idx % 9216;
    int nc = idx / 9216;
    int cls = nc % 59, n = nc / 59;
    int y = p / 96, x = p % 96;
    const float* ar = att + ((size_t)n * 9216 + p) * 9;
    const float* cp = c6o + (size_t)nc * 9216;
    float a = bias[cls];
#pragma unroll
    for (int ky = 0; ky < 3; ++ky)
#pragma unroll
        for (int kx = 0; kx < 3; ++kx) {
            int yy = y + 2 * ky - 2, xx = x + 2 * kx - 2;
            if (yy >= 0 && yy < 96 && xx >= 0 && xx < 96)
                a = fmaf(ar[ky * 3 + kx], cp[yy * 96 + xx], a);
        }
    out[idx] = a;
}

extern "C" void kernel_launch(void* const* d_in, const int* in_sizes, int n_in,
                              void* d_out, int out_size, void* d_ws, size_t ws_size,
                              hipStream_t stream) {
    const float* c1    = (const float*)d_in[0];
    const float* c2    = (const float*)d_in[1];
    const float* xin   = (const float*)d_in[2];
    const float* w_r1  = (const float*)d_in[3];
    const float* bn_r1 = (const float*)d_in[4];
    const float* w_r2  = (const float*)d_in[5];
    const float* bn_r2 = (const float*)d_in[6];
    const float* w_r3  = (const float*)d_in[7];
    const float* bn_r3 = (const float*)d_in[8];
    const float* w_p1  = (const float*)d_in[9];
    const float* bn_p1 = (const float*)d_in[10];
    const float* w_p2  = (const float*)d_in[11];
    const float* bn_p2 = (const float*)d_in[12];
    const float* w_p3  = (const float*)d_in[13];
    const float* bn_p3 = (const float*)d_in[14];
    const float* w_p4  = (const float*)d_in[15];
    const float* bn_p4 = (const float*)d_in[16];
    const float* w_c5  = (const float*)d_in[17];
    const float* bn_c5 = (const float*)d_in[18];
    const float* w_c6  = (const float*)d_in[19];
    const float* b_c6  = (const float*)d_in[20];
    float* out = (float*)d_out;
    (void)in_sizes; (void)n_in; (void)out_size; (void)ws_size;

    char* base = (char*)d_ws;
    float* att = (float*)base;                    // 663,552 B
    char*  A   = base + 663552;
    // ---- phase 1 layout (region A) ----
    hbf*   c1t   = (hbf*)A;                       // 10,240,000
    hbf*   r1t   = (hbf*)(A + 10240000);          //  2,560,000
    float* r1acc = (float*)(A + 12800000);        //  4,718,592
    float* qacc  = (float*)(A + 17518592);        //  4,718,592
    float* c2acc = (float*)(A + 22237184);        //  1,179,648  (fill ends 23,416,832)
    float* q     = (float*)(A + 23416832);        //  4,718,592
    float* c2r   = (float*)(A + 28135424);        //  4,718,592
    hbf*   wr1t  = (hbf*)(A + 32854016);          //    294,912
    hbf*   wr2t  = (hbf*)(A + 33148928);          //     73,728  (ends 33,222,656)
    // ---- phase 2 early (region A): wpsp aliased under xtp, consumed pre-fill ----
    hbf*   wpsp   = (hbf*)A;                      // 18,874,368 (< xtp's 20,480,000)
    float* pooled = (float*)(A + 48791552);       //    819,200
    float* pconv  = (float*)(A + 49610752);       //    204,800
    float* M      = (float*)(A + 49815552);       //  1,843,200  (ends 51,658,752)
    // ---- phase 2 main (region A, reuses wpsp space) ----
    hbf*   xtp    = (hbf*)A;                      // 20,480,000
    float* c5acc  = (float*)(A + 20480000);       //  9,437,184
    hbf*   wt     = (hbf*)(A + 29917184);         // 18,874,368
    // ---- phase 2b (after conv5), aliased over xtp ----
    hbf*   c5out = (hbf*)A;                       //  4,718,592
    float* c6s   = (float*)(A + 4718592);         //  1,087,488
    float* c6o   = (float*)(A + 5806080);         //  4,349,952  (ends 10,156,032)
    // total ws: 663,552 + 51,658,752 = 52,322,304 B (unchanged)

    // ---- phase 1: attention branch ----
    k_fill0<<<dim3(22868), 256, 0, stream>>>((uint32_t*)A, 5854208);
    k_c1trans<<<dim3(288, 8, 2), dim3(32, 8), 0, stream>>>(c1, c1t);
    k_wtrans_small<256><<<dim3(64), 256, 0, stream>>>(w_r1, wr1t);
    k_wtrans_small<64><<<dim3(16), 256, 0, stream>>>(w_r2, wr2t);
    k_dconv_mfma<256><<<dim3(288, 3), 256, 0, stream>>>(wr1t, c1t, r1acc);
    k_ep_r1<<<dim3(72), 256, 0, stream>>>(r1acc, bn_r1, r1t);
    k_dconv_mfma<64><<<dim3(288, 3), 256, 0, stream>>>(wr2t, r1t, qacc);
    k_ep_q<<<dim3(4608), 256, 0, stream>>>(qacc, bn_r2, q);
    k_conv1x1_c2<<<dim3(16, 12, 8), dim3(48, 4), 0, stream>>>(c2, w_r3, c2acc);
    k_up96<<<dim3(2 * 64 * 9216 / 256), 256, 0, stream>>>(c2acc, c2r, 64, bn_r3);
    k_attention<<<dim3(2 * 9216 / 256), 256, 0, stream>>>(q, c2r, att);
    // ---- phase 2: psp branch ----
    k_pool<<<dim3(4096), 64, 0, stream>>>(xin, pooled);
    k_pconv2<<<dim3(512, 2), 64, 0, stream>>>(pooled, w_p1, bn_p1, w_p2, bn_p2,
                                              w_p3, bn_p3, w_p4, bn_p4, pconv);
    k_wpsp_trans<<<dim3(8, 4, 8), 256, 0, stream>>>(w_c5, wpsp);
    k_computeM2<<<dim3(8, 9, 14), 64, 0, stream>>>(wpsp, pconv, M);
    k_fill0<<<dim3(29216), 256, 0, stream>>>((uint32_t*)xtp, 7479296);
    k_xtrans<<<dim3(72, 64, 2), dim3(32, 8), 0, stream>>>(xin, xtp);
    k_wtrans<<<dim3(4096), 256, 0, stream>>>(w_c5, wt);
    k_conv5_mfma<<<dim3(4, 36, 3), 256, 0, stream>>>(wt, xtp, c5acc);
    k_bnrelu_psp<<<dim3(512, 2), 256, 0, stream>>>(c5acc, M, bn_c5, c5out);
    // classifier (conv6 commuted before upsample) + attention aggregation
    k_conv6s<<<dim3(59, 12, 2), dim3(48, 4), 0, stream>>>(c5out, w_c6, c6s);
    k_up96<<<dim3(2 * 59 * 9216 / 256), 256, 0, stream>>>(c6s, c6o, 59, nullptr);
    k_final<<<dim3(2 * 59 * 9216 / 256), 256, 0, stream>>>(att, c6o, b_c6, out);
}